// Round 3
// baseline (255.076 us; speedup 1.0000x reference)
//
#include <hip/hip_runtime.h>
#include <hip/hip_bf16.h>
#include <hip/hip_fp16.h>

// CRF NLL, B=256, T=1024, L=64.
// Hybrid: per batch, fwd vector chain covers emissions [0,G), nm=(sl-G)>>LOGG
// MFMA segments cover [G, G*(1+nm)) as 64x64 linear-domain products
// M_s = prod(diag(E_t) V^T), bwd vector chain covers the <G tail.
// Matrix segments use mfma_f32_16x16x16f16 on a 4x4 grid of 16x16 tiles:
// the C/D register map (row=4H+reg, col=lane&15) is IDENTICAL to the B-operand
// map (k=4H+e, n=lane&15), so C->B repack is just in-lane cvt_pkrtz — no
// permlane, no DPP, no cross-lane ops in the serial loop. Per-step exact pow-2
// renorm folded into next step's diag(E). G=64 (G=128 fallback if ws small).

typedef _Float16 h2 __attribute__((ext_vector_type(2)));
typedef _Float16 half4v __attribute__((ext_vector_type(4)));
typedef float f32x4 __attribute__((ext_vector_type(4)));
typedef unsigned u32x2 __attribute__((ext_vector_type(2)));
typedef unsigned u32x4 __attribute__((ext_vector_type(4)));

#define B2U(x) __builtin_bit_cast(unsigned, x)
#define U2H(x) __builtin_bit_cast(h2, x)
#define L2E 1.44269504088896340736f
#define LN2 0.69314718055994530942f
#define EXPE(p) __builtin_amdgcn_exp2f((p) * L2E)
#define SBAR __builtin_amdgcn_sched_barrier(0)

// ---------------- vector-chain machinery (unchanged, verified) ----------------

#define W_ALL(M) M(0) M(1) M(2) M(3) M(4) M(5) M(6) M(7) M(8) M(9) M(10) M(11) \
 M(12) M(13) M(14) M(15) M(16) M(17) M(18) M(19) M(20) M(21) M(22) M(23) M(24) \
 M(25) M(26) M(27) M(28) M(29) M(30) M(31)

#define DECLW(q) unsigned W##q;
#define LOADF(q) W##q = B2U(__builtin_amdgcn_cvt_pkrtz(EXPE(tcol[(2*(q))*66]), EXPE(tcol[(2*(q)+1)*66])));
#define LOADB(q) W##q = B2U(__builtin_amdgcn_cvt_pkrtz(EXPE(trow[2*(q)]), EXPE(trow[2*(q)+1])));
#define PINW(q)  asm volatile("" : "+v"(W##q));

#define RLD(q) int u##q = __builtin_amdgcn_readlane((int)P, 2*(q));
#define RL16A RLD(0) RLD(1) RLD(2) RLD(3) RLD(4) RLD(5) RLD(6) RLD(7) \
              RLD(8) RLD(9) RLD(10) RLD(11) RLD(12) RLD(13) RLD(14) RLD(15)
#define RL16B RLD(16) RLD(17) RLD(18) RLD(19) RLD(20) RLD(21) RLD(22) RLD(23) \
              RLD(24) RLD(25) RLD(26) RLD(27) RLD(28) RLD(29) RLD(30) RLD(31)

#if __has_builtin(__builtin_amdgcn_fdot2)
#define DOTQ(q, acc) acc = __builtin_amdgcn_fdot2(U2H((unsigned)u##q), U2H(W##q), acc, false);
#else
#define DOTQ(q, acc) { h2 _u = U2H((unsigned)u##q), _w = U2H(W##q); \
    acc = fmaf((float)_u[0], (float)_w[0], fmaf((float)_u[1], (float)_w[1], acc)); }
#endif
#define DOT16A \
    DOTQ(0,s0)  DOTQ(1,s1)  DOTQ(2,s2)  DOTQ(3,s3)  DOTQ(4,s0)  DOTQ(5,s1) \
    DOTQ(6,s2)  DOTQ(7,s3)  DOTQ(8,s0)  DOTQ(9,s1)  DOTQ(10,s2) DOTQ(11,s3) \
    DOTQ(12,s0) DOTQ(13,s1) DOTQ(14,s2) DOTQ(15,s3)
#define DOT16B \
    DOTQ(16,s0) DOTQ(17,s1) DOTQ(18,s2) DOTQ(19,s3) DOTQ(20,s0) DOTQ(21,s1) \
    DOTQ(22,s2) DOTQ(23,s3) DOTQ(24,s0) DOTQ(25,s1) DOTQ(26,s2) DOTQ(27,s3) \
    DOTQ(28,s0) DOTQ(29,s1) DOTQ(30,s2) DOTQ(31,s3)

#define ROWF(i) pb[(((i) < 0) ? 0 : (((i) > 1023) ? 1023 : (i))) * 64]

#define DPPSWAP(x) __uint_as_float((unsigned)__builtin_amdgcn_mov_dpp( \
    (int)__float_as_uint(x), 0xB1, 0xF, 0xF, true))

#define STEPX(E) { \
    unsigned abits = (unsigned)__builtin_amdgcn_readfirstlane((int)__float_as_uint(a)); \
    int k = (int)((abits >> 23) & 255u) - 122; \
    K += k; \
    float sc = __uint_as_float((unsigned)(127 - k) << 23); \
    float x = FWD ? a * sc : (a * sc) * (E); \
    float xo = DPPSWAP(x); \
    unsigned P = B2U(__builtin_amdgcn_cvt_pkrtz(x, xo)); \
    float s0 = 0.f, s1 = 0.f, s2 = 0.f, s3 = 0.f; \
    RL16A \
    SBAR; \
    DOT16A \
    RL16B \
    SBAR; \
    DOT16B \
    float s = (s0 + s1) + (s2 + s3); \
    a = FWD ? s * (E) : s; }

template<bool FWD>
__device__ __forceinline__ void chain(const float* __restrict__ pred,
                                      const float* __restrict__ trans,
                                      int b, int lane, int sl, int h,
                                      float* __restrict__ wsV,
                                      int* __restrict__ wsK)
{
    const float* pb   = pred + (size_t)b * 65536 + lane;
    const float* tcol = trans + lane;        // fwd: V[i][lane]
    const float* trow = trans + lane * 66;   // bwd: V[lane][i]
    (void)tcol; (void)trow;

    W_ALL(DECLW)
    if (FWD) { W_ALL(LOADF) } else { W_ALL(LOADB) }
    W_ALL(PINW)

    float a;
    int   K = 0;
    if (FWD) a = __builtin_amdgcn_exp2f((pb[0] + trans[64 * 66 + lane]) * L2E);
    else     a = __builtin_amdgcn_exp2f(trow[65] * L2E);

    const int dir = FWD ? 1 : -1;
    int n = FWD ? h - 1 : sl - h;
    int r = FWD ? 1 : sl - 1;

    float E0 = EXPE(ROWF(r)), E1 = EXPE(ROWF(r + dir)),
          E2 = EXPE(ROWF(r + 2 * dir)), E3 = EXPE(ROWF(r + 3 * dir));
    while (n >= 4) {
        float F0 = ROWF(r + 4 * dir), F1 = ROWF(r + 5 * dir),
              F2 = ROWF(r + 6 * dir), F3 = ROWF(r + 7 * dir);
        STEPX(E0) STEPX(E1) STEPX(E2) STEPX(E3)
        E0 = EXPE(F0); E1 = EXPE(F1); E2 = EXPE(F2); E3 = EXPE(F3);
        r += 4 * dir; n -= 4;
    }
    if (n > 0) { STEPX(E0) --n; }
    if (n > 0) { STEPX(E1) --n; }
    if (n > 0) { STEPX(E2) }

    wsV[b * 64 + lane] = a;
    if (lane == 0) wsK[b] = K;
}

// ---------------- matrix-segment machinery (16x16x16, zero-shuffle repack) ----

#define MF16(a, b, c) __builtin_amdgcn_mfma_f32_16x16x16f16(a, b, c, 0, 0, 0)

#define MKE(es) __builtin_bit_cast(half4v, (u32x2){ \
    B2U(__builtin_amdgcn_cvt_pkrtz((es), (es))), \
    B2U(__builtin_amdgcn_cvt_pkrtz((es), (es))) })

#define MBROW(mb, EV) { \
    half4v A0 = VA[mb][0]*(EV), A1 = VA[mb][1]*(EV), \
           A2 = VA[mb][2]*(EV), A3 = VA[mb][3]*(EV); \
    _Pragma("unroll") \
    for (int nb = 0; nb < 4; ++nb) { \
        f32x4 acc = {0.f, 0.f, 0.f, 0.f}; \
        acc = MF16(A0, Bf[0][nb], acc); \
        acc = MF16(A1, Bf[1][nb], acc); \
        acc = MF16(A2, Bf[2][nb], acc); \
        acc = MF16(A3, Bf[3][nb], acc); \
        Cn[mb][nb] = acc; } }

template<int LOGG, int NSLOT>
__device__ __forceinline__ void midseg(const float* __restrict__ pred,
                                       const float* __restrict__ trans,
                                       int b, int lane, int sl, int s,
                                       _Float16* __restrict__ wsM,
                                       int* __restrict__ wsKm)
{
    const int G  = 1 << LOGG;
    const int nm = (sl - G) >> LOGG;
    if (s >= nm) return;
    const int t0 = G * (1 + s);
    const int H  = lane >> 4;       // 0..3
    const int j0 = lane & 15;

    // A-basis: VA[mb][kb][e] = exp(trans[k][m]), m=16mb+j0, k=16kb+4H+e.
    half4v VA[4][4];
    #pragma unroll
    for (int mb = 0; mb < 4; ++mb)
        #pragma unroll
        for (int kb = 0; kb < 4; ++kb) {
            const float* tp = trans + (16*kb + 4*H) * 66 + 16*mb + j0;
            u32x2 q;
            q.x = B2U(__builtin_amdgcn_cvt_pkrtz(EXPE(tp[0]),   EXPE(tp[66])));
            q.y = B2U(__builtin_amdgcn_cvt_pkrtz(EXPE(tp[132]), EXPE(tp[198])));
            VA[mb][kb] = __builtin_bit_cast(half4v, q);
        }

    // B starts as identity.
    half4v Bf[4][4];   // [kb][nb]
    #pragma unroll
    for (int kb = 0; kb < 4; ++kb)
        #pragma unroll
        for (int nb = 0; nb < 4; ++nb) {
            half4v bb;
            #pragma unroll
            for (int e = 0; e < 4; ++e)
                bb[e] = (16*kb + 4*H + e == 16*nb + j0) ? (_Float16)1.f
                                                        : (_Float16)0.f;
            Bf[kb][nb] = bb;
        }

    const float* pp = pred + (size_t)b * 65536 + j0;
    float eA0 = EXPE(pp[(size_t)t0*64]),      eA1 = EXPE(pp[(size_t)t0*64+16]),
          eA2 = EXPE(pp[(size_t)t0*64+32]),   eA3 = EXPE(pp[(size_t)t0*64+48]);
    float eB0 = EXPE(pp[(size_t)(t0+1)*64]),    eB1 = EXPE(pp[(size_t)(t0+1)*64+16]),
          eB2 = EXPE(pp[(size_t)(t0+1)*64+32]), eB3 = EXPE(pp[(size_t)(t0+1)*64+48]);

    f32x4 C[4][4];
    #pragma unroll
    for (int mb = 0; mb < 4; ++mb)
        #pragma unroll
        for (int nb = 0; nb < 4; ++nb)
            C[mb][nb] = (f32x4){0.f, 0.f, 0.f, 0.f};

    int   K   = 0;
    float scf = 1.0f;

    for (int i = 0; i < G; ++i) {
        int tn = t0 + i + 2; if (tn > 1023) tn = 1023;
        float g0 = pp[(size_t)tn*64],    g1 = pp[(size_t)tn*64+16],
              g2 = pp[(size_t)tn*64+32], g3 = pp[(size_t)tn*64+48];

        if (i > 0) {
            // renorm ref: 16 rows {0-3,16-19,32-35,48-51} of col 0 at lane 0
            float sr = ((C[0][0][0]+C[0][0][1])+(C[0][0][2]+C[0][0][3]))
                     + ((C[1][0][0]+C[1][0][1])+(C[1][0][2]+C[1][0][3]))
                     + ((C[2][0][0]+C[2][0][1])+(C[2][0][2]+C[2][0][3]))
                     + ((C[3][0][0]+C[3][0][1])+(C[3][0][2]+C[3][0][3]));
            unsigned cb = (unsigned)__builtin_amdgcn_readfirstlane((int)__float_as_uint(sr));
            int kk = (int)((cb >> 23) & 255u) - 129;   // ilogb(sr) - 2
            K += kk;
            scf = __uint_as_float((unsigned)(127 - kk) << 23);
            // C -> B: pure in-lane cvt (layouts identical)
            #pragma unroll
            for (int kb = 0; kb < 4; ++kb)
                #pragma unroll
                for (int nb = 0; nb < 4; ++nb) {
                    u32x2 q;
                    q.x = B2U(__builtin_amdgcn_cvt_pkrtz(C[kb][nb][0], C[kb][nb][1]));
                    q.y = B2U(__builtin_amdgcn_cvt_pkrtz(C[kb][nb][2], C[kb][nb][3]));
                    Bf[kb][nb] = __builtin_bit_cast(half4v, q);
                }
        }

        float es0 = eA0*scf, es1 = eA1*scf, es2 = eA2*scf, es3 = eA3*scf;
        half4v E0 = MKE(es0), E1 = MKE(es1), E2 = MKE(es2), E3 = MKE(es3);

        f32x4 Cn[4][4];
        MBROW(0, E0) MBROW(1, E1) MBROW(2, E2) MBROW(3, E3)
        #pragma unroll
        for (int mb = 0; mb < 4; ++mb)
            #pragma unroll
            for (int nb = 0; nb < 4; ++nb)
                C[mb][nb] = Cn[mb][nb];

        eA0 = eB0; eA1 = eB1; eA2 = eB2; eA3 = eB3;
        eB0 = EXPE(g0); eB1 = EXPE(g1); eB2 = EXPE(g2); eB3 = EXPE(g3);
    }

    // store M_s row-major f16 [64][64]
    _Float16* wm = wsM + ((size_t)b * NSLOT + s) * 4096;
    #pragma unroll
    for (int mb = 0; mb < 4; ++mb)
        #pragma unroll
        for (int nb = 0; nb < 4; ++nb)
            #pragma unroll
            for (int r = 0; r < 4; ++r)
                wm[(16*mb + 4*H + r) * 64 + 16*nb + j0] = (_Float16)C[mb][nb][r];
    if (lane == 0) wsKm[b * NSLOT + s] = K;
}

// ---------------- kernels ----------------

template<int LOGG, int NSLOT>
__global__ __launch_bounds__(64)
void chain_kernel(const float* __restrict__ pred,
                  const float* __restrict__ trans,
                  const int*   __restrict__ ref,
                  const int*   __restrict__ seqlen,
                  float* __restrict__ wsA, float* __restrict__ wsB,
                  int* __restrict__ wsKf, int* __restrict__ wsKb,
                  _Float16* __restrict__ wsM, int* __restrict__ wsKm,
                  float* __restrict__ out)
{
    const int role = blockIdx.x >> 8;
    const int b    = blockIdx.x & 255;
    const int lane = threadIdx.x;
    const int sl   = seqlen[b];
    const int G    = 1 << LOGG;

    if (role == 0) {
        chain<true>(pred, trans, b, lane, sl, G, wsA, wsKf);
    } else if (role == 1) {
        const int nm = (sl - G) >> LOGG;
        chain<false>(pred, trans, b, lane, sl, G * (1 + nm), wsB, wsKb);
    } else if (role == 2) {
        // gold-path score
        const int*   rb = ref  + b * 1024;
        const float* pg = pred + (size_t)b * 65536;
        float acc = 0.f;
        for (int t = lane; t <= sl; t += 64) {
            int from = (t == 0) ? 64 : rb[t - 1];
            int cur  = (t < sl) ? rb[t] : 65;
            acc += trans[from * 66 + cur];
            if (t < sl) acc += pg[t * 64 + cur];
        }
        #pragma unroll
        for (int off = 32; off; off >>= 1) acc += __shfl_xor(acc, off, 64);
        if (lane == 0) atomicAdd(out, -acc);
    } else {
        midseg<LOGG, NSLOT>(pred, trans, b, lane, sl, role - 3, wsM, wsKm);
    }
}

template<int LOGG, int NSLOT>
__global__ __launch_bounds__(64) void combine_kernel(
    const float* __restrict__ wsA, const float* __restrict__ wsB,
    const _Float16* __restrict__ wsM,
    const int* __restrict__ wsKf, const int* __restrict__ wsKb,
    const int* __restrict__ wsKm, const int* __restrict__ seqlen,
    float* __restrict__ out)
{
    const int b = blockIdx.x, j = threadIdx.x;
    const int sl = seqlen[b];
    const int nm = (sl - (1 << LOGG)) >> LOGG;

    float v = wsA[b * 64 + j];
    int   K = wsKf[b] + wsKb[b];
    const _Float16* mrow = wsM + (size_t)b * NSLOT * 4096 + j * 64;  // row j

    for (int s = 0; s < nm; ++s) {
        K += wsKm[b * NSLOT + s];
        const u32x4* mp = (const u32x4*)(mrow + (size_t)s * 4096);
        u32x4 L0 = mp[0], L1 = mp[1], L2 = mp[2], L3 = mp[3],
              L4 = mp[4], L5 = mp[5], L6 = mp[6], L7 = mp[7];
        unsigned mw[32] = {L0.x,L0.y,L0.z,L0.w, L1.x,L1.y,L1.z,L1.w,
                           L2.x,L2.y,L2.z,L2.w, L3.x,L3.y,L3.z,L3.w,
                           L4.x,L4.y,L4.z,L4.w, L5.x,L5.y,L5.z,L5.w,
                           L6.x,L6.y,L6.z,L6.w, L7.x,L7.y,L7.z,L7.w};
        float av[4] = {0.f, 0.f, 0.f, 0.f};
        #pragma unroll
        for (int q = 0; q < 32; ++q) {
            h2 p = U2H(mw[q]);
            float v0 = __uint_as_float((unsigned)
                __builtin_amdgcn_readlane((int)__float_as_uint(v), 2*q));
            float v1 = __uint_as_float((unsigned)
                __builtin_amdgcn_readlane((int)__float_as_uint(v), 2*q + 1));
            av[q & 3] = fmaf((float)p[0], v0, fmaf((float)p[1], v1, av[q & 3]));
        }
        float acc = (av[0] + av[1]) + (av[2] + av[3]);
        unsigned ab = (unsigned)__builtin_amdgcn_readfirstlane((int)__float_as_uint(acc));
        int k2 = (int)((ab >> 23) & 255u) - 127;
        K += k2;
        v = acc * __uint_as_float((unsigned)(127 - k2) << 23);
    }

    float z = v * wsB[b * 64 + j];
    #pragma unroll
    for (int off = 32; off; off >>= 1) z += __shfl_xor(z, off, 64);
    if (j == 0) {
        float res = LN2 * (__builtin_amdgcn_logf(z) + (float)K);
        atomicAdd(out, res);
    }
}

// ---------------- launch ----------------

template<int LOGG, int NSLOT>
static void launch_all(const float* pred, const float* trans, const int* ref,
                       const int* seqlen, float* out, void* d_ws,
                       hipStream_t stream)
{
    float* wsA  = (float*)d_ws;            // 256*64 f32
    float* wsB  = wsA + 256 * 64;          // 256*64 f32
    int*   wsKf = (int*)(wsB + 256 * 64);  // 256 i32
    int*   wsKb = wsKf + 256;              // 256 i32
    int*   wsKm = wsKb + 256;              // 256*NSLOT i32
    _Float16* wsM = (_Float16*)(wsKm + 256 * NSLOT);  // 256*NSLOT*4096 f16

    hipMemsetAsync(out, 0, sizeof(float), stream);
    chain_kernel<LOGG, NSLOT><<<256 * (3 + NSLOT), 64, 0, stream>>>(
        pred, trans, ref, seqlen, wsA, wsB, wsKf, wsKb, wsM, wsKm, out);
    combine_kernel<LOGG, NSLOT><<<256, 64, 0, stream>>>(
        wsA, wsB, wsM, wsKf, wsKb, wsKm, seqlen, out);
}

extern "C" void kernel_launch(void* const* d_in, const int* in_sizes, int n_in,
                              void* d_out, int out_size, void* d_ws, size_t ws_size,
                              hipStream_t stream) {
    const float* pred   = (const float*)d_in[0];
    const float* trans  = (const float*)d_in[1];
    const int*   ref    = (const int*)d_in[2];
    const int*   seqlen = (const int*)d_in[3];
    float* out = (float*)d_out;

    // G=64 needs 2*64KB + 2*1KB + 15KB + 30MB ≈ 31.6 MB; fall back to the
    // round-1-proven G=128 geometry (14.8 MB) if the workspace is smaller.
    const size_t need64 = 2*65536 + 2*1024 + (size_t)256*15*4
                        + (size_t)256*15*4096*2;
    if (ws_size >= need64)
        launch_all<6, 15>(pred, trans, ref, seqlen, out, d_ws, stream);
    else
        launch_all<7, 7>(pred, trans, ref, seqlen, out, d_ws, stream);
}

// Round 6
// 222.384 us; speedup vs baseline: 1.1470x; 1.1470x over previous
//
#include <hip/hip_runtime.h>
#include <hip/hip_bf16.h>
#include <hip/hip_fp16.h>

// CRF NLL, B=256, T=1024, L=64.
// Hybrid: per batch, fwd vector chain covers emissions [0,G), nm=(sl-G)>>LOGG
// MFMA segments cover [G, G*(1+nm)) as 64x64 linear-domain products
// M_s = prod(diag(E_t) V^T), bwd vector chain covers the <G tail.
// Matrix segments use mfma_f32_16x16x32_f16 (CDNA4-native 2xK shape) on a
// 4x4 grid of 16x16 C-tiles, 2 K-slices of 32. Slot->k bijection chosen as
// {e<4: k=4H+e, e>=4: k=16+4H+e-4} per 32-slice for BOTH A and B (self-
// consistent => correct regardless of HW's internal k-order), which makes the
// C->B repack pure in-lane cvt_pkrtz: Bf(ks,nb) = concat(cvt4(C[2ks][nb]),
// cvt4(C[2ks+1][nb])). No cross-lane ops, no C copies (C rebuilt in place).
// Per-step exact pow-2 renorm folded into next step's diag(E).

typedef _Float16 h2 __attribute__((ext_vector_type(2)));
typedef _Float16 half8 __attribute__((ext_vector_type(8)));
typedef float f32x4 __attribute__((ext_vector_type(4)));
typedef unsigned u32x2 __attribute__((ext_vector_type(2)));
typedef unsigned u32x4 __attribute__((ext_vector_type(4)));

#define B2U(x) __builtin_bit_cast(unsigned, x)
#define U2H(x) __builtin_bit_cast(h2, x)
#define L2E 1.44269504088896340736f
#define LN2 0.69314718055994530942f
#define EXPE(p) __builtin_amdgcn_exp2f((p) * L2E)
#define SBAR __builtin_amdgcn_sched_barrier(0)

// ---------------- vector-chain machinery (unchanged, verified) ----------------

#define W_ALL(M) M(0) M(1) M(2) M(3) M(4) M(5) M(6) M(7) M(8) M(9) M(10) M(11) \
 M(12) M(13) M(14) M(15) M(16) M(17) M(18) M(19) M(20) M(21) M(22) M(23) M(24) \
 M(25) M(26) M(27) M(28) M(29) M(30) M(31)

#define DECLW(q) unsigned W##q;
#define LOADF(q) W##q = B2U(__builtin_amdgcn_cvt_pkrtz(EXPE(tcol[(2*(q))*66]), EXPE(tcol[(2*(q)+1)*66])));
#define LOADB(q) W##q = B2U(__builtin_amdgcn_cvt_pkrtz(EXPE(trow[2*(q)]), EXPE(trow[2*(q)+1])));
#define PINW(q)  asm volatile("" : "+v"(W##q));

#define RLD(q) int u##q = __builtin_amdgcn_readlane((int)P, 2*(q));
#define RL16A RLD(0) RLD(1) RLD(2) RLD(3) RLD(4) RLD(5) RLD(6) RLD(7) \
              RLD(8) RLD(9) RLD(10) RLD(11) RLD(12) RLD(13) RLD(14) RLD(15)
#define RL16B RLD(16) RLD(17) RLD(18) RLD(19) RLD(20) RLD(21) RLD(22) RLD(23) \
              RLD(24) RLD(25) RLD(26) RLD(27) RLD(28) RLD(29) RLD(30) RLD(31)

#if __has_builtin(__builtin_amdgcn_fdot2)
#define DOTQ(q, acc) acc = __builtin_amdgcn_fdot2(U2H((unsigned)u##q), U2H(W##q), acc, false);
#else
#define DOTQ(q, acc) { h2 _u = U2H((unsigned)u##q), _w = U2H(W##q); \
    acc = fmaf((float)_u[0], (float)_w[0], fmaf((float)_u[1], (float)_w[1], acc)); }
#endif
#define DOT16A \
    DOTQ(0,s0)  DOTQ(1,s1)  DOTQ(2,s2)  DOTQ(3,s3)  DOTQ(4,s0)  DOTQ(5,s1) \
    DOTQ(6,s2)  DOTQ(7,s3)  DOTQ(8,s0)  DOTQ(9,s1)  DOTQ(10,s2) DOTQ(11,s3) \
    DOTQ(12,s0) DOTQ(13,s1) DOTQ(14,s2) DOTQ(15,s3)
#define DOT16B \
    DOTQ(16,s0) DOTQ(17,s1) DOTQ(18,s2) DOTQ(19,s3) DOTQ(20,s0) DOTQ(21,s1) \
    DOTQ(22,s2) DOTQ(23,s3) DOTQ(24,s0) DOTQ(25,s1) DOTQ(26,s2) DOTQ(27,s3) \
    DOTQ(28,s0) DOTQ(29,s1) DOTQ(30,s2) DOTQ(31,s3)

#define ROWF(i) pb[(((i) < 0) ? 0 : (((i) > 1023) ? 1023 : (i))) * 64]

#define DPPSWAP(x) __uint_as_float((unsigned)__builtin_amdgcn_mov_dpp( \
    (int)__float_as_uint(x), 0xB1, 0xF, 0xF, true))

#define STEPX(E) { \
    unsigned abits = (unsigned)__builtin_amdgcn_readfirstlane((int)__float_as_uint(a)); \
    int k = (int)((abits >> 23) & 255u) - 122; \
    K += k; \
    float sc = __uint_as_float((unsigned)(127 - k) << 23); \
    float x = FWD ? a * sc : (a * sc) * (E); \
    float xo = DPPSWAP(x); \
    unsigned P = B2U(__builtin_amdgcn_cvt_pkrtz(x, xo)); \
    float s0 = 0.f, s1 = 0.f, s2 = 0.f, s3 = 0.f; \
    RL16A \
    SBAR; \
    DOT16A \
    RL16B \
    SBAR; \
    DOT16B \
    float s = (s0 + s1) + (s2 + s3); \
    a = FWD ? s * (E) : s; }

template<bool FWD>
__device__ __forceinline__ void chain(const float* __restrict__ pred,
                                      const float* __restrict__ trans,
                                      int b, int lane, int sl, int h,
                                      float* __restrict__ wsV,
                                      int* __restrict__ wsK)
{
    const float* pb   = pred + (size_t)b * 65536 + lane;
    const float* tcol = trans + lane;        // fwd: V[i][lane]
    const float* trow = trans + lane * 66;   // bwd: V[lane][i]
    (void)tcol; (void)trow;

    W_ALL(DECLW)
    if (FWD) { W_ALL(LOADF) } else { W_ALL(LOADB) }
    W_ALL(PINW)

    float a;
    int   K = 0;
    if (FWD) a = __builtin_amdgcn_exp2f((pb[0] + trans[64 * 66 + lane]) * L2E);
    else     a = __builtin_amdgcn_exp2f(trow[65] * L2E);

    const int dir = FWD ? 1 : -1;
    int n = FWD ? h - 1 : sl - h;
    int r = FWD ? 1 : sl - 1;

    float E0 = EXPE(ROWF(r)), E1 = EXPE(ROWF(r + dir)),
          E2 = EXPE(ROWF(r + 2 * dir)), E3 = EXPE(ROWF(r + 3 * dir));
    while (n >= 4) {
        float F0 = ROWF(r + 4 * dir), F1 = ROWF(r + 5 * dir),
              F2 = ROWF(r + 6 * dir), F3 = ROWF(r + 7 * dir);
        STEPX(E0) STEPX(E1) STEPX(E2) STEPX(E3)
        E0 = EXPE(F0); E1 = EXPE(F1); E2 = EXPE(F2); E3 = EXPE(F3);
        r += 4 * dir; n -= 4;
    }
    if (n > 0) { STEPX(E0) --n; }
    if (n > 0) { STEPX(E1) --n; }
    if (n > 0) { STEPX(E2) }

    wsV[b * 64 + lane] = a;
    if (lane == 0) wsK[b] = K;
}

// ---------------- matrix-segment machinery (16x16x32, zero-shuffle repack) ----

#define MF32(a, b, c) __builtin_amdgcn_mfma_f32_16x16x32_f16(a, b, c, 0, 0, 0)

// slot->k bijection within a 32-k slice: e<4 -> 4H+e ; e>=4 -> 16+4H+(e-4)
#define KG(ks, H, e) (32*(ks) + (((e) < 4) ? (4*(H) + (e)) : (16 + 4*(H) + (e) - 4)))

template<int LOGG, int NSLOT>
__device__ __forceinline__ void midseg(const float* __restrict__ pred,
                                       const float* __restrict__ trans,
                                       int b, int lane, int sl, int s,
                                       _Float16* __restrict__ wsM,
                                       int* __restrict__ wsKm)
{
    const int G  = 1 << LOGG;
    const int nm = (sl - G) >> LOGG;
    if (s >= nm) return;
    const int t0 = G * (1 + s);
    const int H  = lane >> 4;       // 0..3
    const int j0 = lane & 15;

    const f32x4 Z4 = {0.f, 0.f, 0.f, 0.f};

    // A-basis: VA[mb][ks] slot e holds exp(trans[KG(ks,H,e)][16mb+j0]).
    half8 VA[4][2];
    #pragma unroll
    for (int mb = 0; mb < 4; ++mb)
        #pragma unroll
        for (int ks = 0; ks < 2; ++ks) {
            const float* tp = trans + 16*mb + j0;
            u32x4 q;
            q.x = B2U(__builtin_amdgcn_cvt_pkrtz(EXPE(tp[KG(ks,H,0)*66]), EXPE(tp[KG(ks,H,1)*66])));
            q.y = B2U(__builtin_amdgcn_cvt_pkrtz(EXPE(tp[KG(ks,H,2)*66]), EXPE(tp[KG(ks,H,3)*66])));
            q.z = B2U(__builtin_amdgcn_cvt_pkrtz(EXPE(tp[KG(ks,H,4)*66]), EXPE(tp[KG(ks,H,5)*66])));
            q.w = B2U(__builtin_amdgcn_cvt_pkrtz(EXPE(tp[KG(ks,H,6)*66]), EXPE(tp[KG(ks,H,7)*66])));
            VA[mb][ks] = __builtin_bit_cast(half8, q);
        }

    // B starts as identity (same slot->k bijection).
    half8 Bf[2][4];   // [ks][nb]
    #pragma unroll
    for (int ks = 0; ks < 2; ++ks)
        #pragma unroll
        for (int nb = 0; nb < 4; ++nb) {
            half8 bb;
            #pragma unroll
            for (int e = 0; e < 8; ++e)
                bb[e] = (KG(ks, H, e) == 16*nb + j0) ? (_Float16)1.f
                                                     : (_Float16)0.f;
            Bf[ks][nb] = bb;
        }

    const float* pp = pred + (size_t)b * 65536 + j0;
    float eA0 = EXPE(pp[(size_t)t0*64]),      eA1 = EXPE(pp[(size_t)t0*64+16]),
          eA2 = EXPE(pp[(size_t)t0*64+32]),   eA3 = EXPE(pp[(size_t)t0*64+48]);
    float eB0 = EXPE(pp[(size_t)(t0+1)*64]),    eB1 = EXPE(pp[(size_t)(t0+1)*64+16]),
          eB2 = EXPE(pp[(size_t)(t0+1)*64+32]), eB3 = EXPE(pp[(size_t)(t0+1)*64+48]);

    f32x4 C[4][4];
    #pragma unroll
    for (int mb = 0; mb < 4; ++mb)
        #pragma unroll
        for (int nb = 0; nb < 4; ++nb)
            C[mb][nb] = Z4;

    int   K   = 0;
    float scf = 1.0f;

    for (int i = 0; i < G; ++i) {
        int tn = t0 + i + 2; if (tn > 1023) tn = 1023;
        float g0 = pp[(size_t)tn*64],    g1 = pp[(size_t)tn*64+16],
              g2 = pp[(size_t)tn*64+32], g3 = pp[(size_t)tn*64+48];

        if (i > 0) {
            // renorm ref: 16 rows {0-3,16-19,32-35,48-51} of col 0 at lane 0
            float sr = ((C[0][0][0]+C[0][0][1])+(C[0][0][2]+C[0][0][3]))
                     + ((C[1][0][0]+C[1][0][1])+(C[1][0][2]+C[1][0][3]))
                     + ((C[2][0][0]+C[2][0][1])+(C[2][0][2]+C[2][0][3]))
                     + ((C[3][0][0]+C[3][0][1])+(C[3][0][2]+C[3][0][3]));
            unsigned cb = (unsigned)__builtin_amdgcn_readfirstlane((int)__float_as_uint(sr));
            int kk = (int)((cb >> 23) & 255u) - 129;   // ilogb(sr) - 2
            K += kk;
            scf = __uint_as_float((unsigned)(127 - kk) << 23);
            // C -> B: pure in-lane cvt. Bf(ks,nb) = concat(C[2ks][nb], C[2ks+1][nb])
            #pragma unroll
            for (int ks = 0; ks < 2; ++ks)
                #pragma unroll
                for (int nb = 0; nb < 4; ++nb) {
                    u32x4 q;
                    q.x = B2U(__builtin_amdgcn_cvt_pkrtz(C[2*ks][nb][0],   C[2*ks][nb][1]));
                    q.y = B2U(__builtin_amdgcn_cvt_pkrtz(C[2*ks][nb][2],   C[2*ks][nb][3]));
                    q.z = B2U(__builtin_amdgcn_cvt_pkrtz(C[2*ks+1][nb][0], C[2*ks+1][nb][1]));
                    q.w = B2U(__builtin_amdgcn_cvt_pkrtz(C[2*ks+1][nb][2], C[2*ks+1][nb][3]));
                    Bf[ks][nb] = __builtin_bit_cast(half8, q);
                }
        }

        // E row-scale, one cvt per row-block + splat
        unsigned p0 = B2U(__builtin_amdgcn_cvt_pkrtz(eA0*scf, eA0*scf));
        unsigned p1 = B2U(__builtin_amdgcn_cvt_pkrtz(eA1*scf, eA1*scf));
        unsigned p2 = B2U(__builtin_amdgcn_cvt_pkrtz(eA2*scf, eA2*scf));
        unsigned p3 = B2U(__builtin_amdgcn_cvt_pkrtz(eA3*scf, eA3*scf));
        half8 E0 = __builtin_bit_cast(half8, (u32x4){p0,p0,p0,p0});
        half8 E1 = __builtin_bit_cast(half8, (u32x4){p1,p1,p1,p1});
        half8 E2 = __builtin_bit_cast(half8, (u32x4){p2,p2,p2,p2});
        half8 E3 = __builtin_bit_cast(half8, (u32x4){p3,p3,p3,p3});

        // C rebuilt in place (Bf already captured old C)
        {
            half8 A0 = VA[0][0]*E0, A1 = VA[0][1]*E0;
            #pragma unroll
            for (int nb = 0; nb < 4; ++nb) {
                f32x4 t = MF32(A0, Bf[0][nb], Z4);
                C[0][nb] = MF32(A1, Bf[1][nb], t);
            }
        }
        {
            half8 A0 = VA[1][0]*E1, A1 = VA[1][1]*E1;
            #pragma unroll
            for (int nb = 0; nb < 4; ++nb) {
                f32x4 t = MF32(A0, Bf[0][nb], Z4);
                C[1][nb] = MF32(A1, Bf[1][nb], t);
            }
        }
        {
            half8 A0 = VA[2][0]*E2, A1 = VA[2][1]*E2;
            #pragma unroll
            for (int nb = 0; nb < 4; ++nb) {
                f32x4 t = MF32(A0, Bf[0][nb], Z4);
                C[2][nb] = MF32(A1, Bf[1][nb], t);
            }
        }
        {
            half8 A0 = VA[3][0]*E3, A1 = VA[3][1]*E3;
            #pragma unroll
            for (int nb = 0; nb < 4; ++nb) {
                f32x4 t = MF32(A0, Bf[0][nb], Z4);
                C[3][nb] = MF32(A1, Bf[1][nb], t);
            }
        }

        eA0 = eB0; eA1 = eB1; eA2 = eB2; eA3 = eB3;
        eB0 = EXPE(g0); eB1 = EXPE(g1); eB2 = EXPE(g2); eB3 = EXPE(g3);
    }

    // store M_s row-major f16 [64][64]
    _Float16* wm = wsM + ((size_t)b * NSLOT + s) * 4096;
    #pragma unroll
    for (int mb = 0; mb < 4; ++mb)
        #pragma unroll
        for (int nb = 0; nb < 4; ++nb)
            #pragma unroll
            for (int r = 0; r < 4; ++r)
                wm[(16*mb + 4*H + r) * 64 + 16*nb + j0] = (_Float16)C[mb][nb][r];
    if (lane == 0) wsKm[b * NSLOT + s] = K;
}

// ---------------- kernels ----------------

template<int LOGG, int NSLOT>
__global__ __launch_bounds__(64)
void chain_kernel(const float* __restrict__ pred,
                  const float* __restrict__ trans,
                  const int*   __restrict__ ref,
                  const int*   __restrict__ seqlen,
                  float* __restrict__ wsA, float* __restrict__ wsB,
                  int* __restrict__ wsKf, int* __restrict__ wsKb,
                  _Float16* __restrict__ wsM, int* __restrict__ wsKm,
                  float* __restrict__ out)
{
    const int role = blockIdx.x >> 8;
    const int b    = blockIdx.x & 255;
    const int lane = threadIdx.x;
    const int sl   = seqlen[b];
    const int G    = 1 << LOGG;

    if (role == 0) {
        chain<true>(pred, trans, b, lane, sl, G, wsA, wsKf);
    } else if (role == 1) {
        const int nm = (sl - G) >> LOGG;
        chain<false>(pred, trans, b, lane, sl, G * (1 + nm), wsB, wsKb);
    } else if (role == 2) {
        // gold-path score
        const int*   rb = ref  + b * 1024;
        const float* pg = pred + (size_t)b * 65536;
        float acc = 0.f;
        for (int t = lane; t <= sl; t += 64) {
            int from = (t == 0) ? 64 : rb[t - 1];
            int cur  = (t < sl) ? rb[t] : 65;
            acc += trans[from * 66 + cur];
            if (t < sl) acc += pg[t * 64 + cur];
        }
        #pragma unroll
        for (int off = 32; off; off >>= 1) acc += __shfl_xor(acc, off, 64);
        if (lane == 0) atomicAdd(out, -acc);
    } else {
        midseg<LOGG, NSLOT>(pred, trans, b, lane, sl, role - 3, wsM, wsKm);
    }
}

template<int LOGG, int NSLOT>
__global__ __launch_bounds__(64) void combine_kernel(
    const float* __restrict__ wsA, const float* __restrict__ wsB,
    const _Float16* __restrict__ wsM,
    const int* __restrict__ wsKf, const int* __restrict__ wsKb,
    const int* __restrict__ wsKm, const int* __restrict__ seqlen,
    float* __restrict__ out)
{
    const int b = blockIdx.x, j = threadIdx.x;
    const int sl = seqlen[b];
    const int nm = (sl - (1 << LOGG)) >> LOGG;

    float v = wsA[b * 64 + j];
    int   K = wsKf[b] + wsKb[b];
    const _Float16* mrow = wsM + (size_t)b * NSLOT * 4096 + j * 64;  // row j

    for (int s = 0; s < nm; ++s) {
        K += wsKm[b * NSLOT + s];
        const u32x4* mp = (const u32x4*)(mrow + (size_t)s * 4096);
        u32x4 L0 = mp[0], L1 = mp[1], L2 = mp[2], L3 = mp[3],
              L4 = mp[4], L5 = mp[5], L6 = mp[6], L7 = mp[7];
        unsigned mw[32] = {L0.x,L0.y,L0.z,L0.w, L1.x,L1.y,L1.z,L1.w,
                           L2.x,L2.y,L2.z,L2.w, L3.x,L3.y,L3.z,L3.w,
                           L4.x,L4.y,L4.z,L4.w, L5.x,L5.y,L5.z,L5.w,
                           L6.x,L6.y,L6.z,L6.w, L7.x,L7.y,L7.z,L7.w};
        float av[4] = {0.f, 0.f, 0.f, 0.f};
        #pragma unroll
        for (int q = 0; q < 32; ++q) {
            h2 p = U2H(mw[q]);
            float v0 = __uint_as_float((unsigned)
                __builtin_amdgcn_readlane((int)__float_as_uint(v), 2*q));
            float v1 = __uint_as_float((unsigned)
                __builtin_amdgcn_readlane((int)__float_as_uint(v), 2*q + 1));
            av[q & 3] = fmaf((float)p[0], v0, fmaf((float)p[1], v1, av[q & 3]));
        }
        float acc = (av[0] + av[1]) + (av[2] + av[3]);
        unsigned ab = (unsigned)__builtin_amdgcn_readfirstlane((int)__float_as_uint(acc));
        int k2 = (int)((ab >> 23) & 255u) - 127;
        K += k2;
        v = acc * __uint_as_float((unsigned)(127 - k2) << 23);
    }

    float z = v * wsB[b * 64 + j];
    #pragma unroll
    for (int off = 32; off; off >>= 1) z += __shfl_xor(z, off, 64);
    if (j == 0) {
        float res = LN2 * (__builtin_amdgcn_logf(z) + (float)K);
        atomicAdd(out, res);
    }
}

// ---------------- launch ----------------

template<int LOGG, int NSLOT>
static void launch_all(const float* pred, const float* trans, const int* ref,
                       const int* seqlen, float* out, void* d_ws,
                       hipStream_t stream)
{
    float* wsA  = (float*)d_ws;            // 256*64 f32
    float* wsB  = wsA + 256 * 64;          // 256*64 f32
    int*   wsKf = (int*)(wsB + 256 * 64);  // 256 i32
    int*   wsKb = wsKf + 256;              // 256 i32
    int*   wsKm = wsKb + 256;              // 256*NSLOT i32
    _Float16* wsM = (_Float16*)(wsKm + 256 * NSLOT);  // 256*NSLOT*4096 f16

    hipMemsetAsync(out, 0, sizeof(float), stream);
    chain_kernel<LOGG, NSLOT><<<256 * (3 + NSLOT), 64, 0, stream>>>(
        pred, trans, ref, seqlen, wsA, wsB, wsKf, wsKb, wsM, wsKm, out);
    combine_kernel<LOGG, NSLOT><<<256, 64, 0, stream>>>(
        wsA, wsB, wsM, wsKf, wsKb, wsKm, seqlen, out);
}

extern "C" void kernel_launch(void* const* d_in, const int* in_sizes, int n_in,
                              void* d_out, int out_size, void* d_ws, size_t ws_size,
                              hipStream_t stream) {
    const float* pred   = (const float*)d_in[0];
    const float* trans  = (const float*)d_in[1];
    const int*   ref    = (const int*)d_in[2];
    const int*   seqlen = (const int*)d_in[3];
    float* out = (float*)d_out;

    // G=64 needs 2*64KB + 2*1KB + 15KB + 30MB ≈ 31.6 MB; fall back to the
    // G=128 geometry (14.8 MB) if the workspace is smaller.
    const size_t need64 = 2*65536 + 2*1024 + (size_t)256*15*4
                        + (size_t)256*15*4096*2;
    if (ws_size >= need64)
        launch_all<6, 15>(pred, trans, ref, seqlen, out, d_ws, stream);
    else
        launch_all<7, 7>(pred, trans, ref, seqlen, out, d_ws, stream);
}

// Round 7
// 212.592 us; speedup vs baseline: 1.1998x; 1.0461x over previous
//
#include <hip/hip_runtime.h>
#include <hip/hip_bf16.h>
#include <hip/hip_fp16.h>

// CRF NLL, B=256, T=1024, L=64.
// Hybrid: per batch, fwd vector chain covers emissions [0,G), nm=(sl-G)>>LOGG
// MFMA segments cover [G, G*(1+nm)) as 64x64 linear-domain products
// M_s = prod(diag(E_t) V^T), bwd vector chain covers the <G tail.
// Matrix segments use mfma_f32_16x16x32_f16 on a 4x4 grid of 16x16 C-tiles,
// 2 K-slices of 32; slot->k bijection consistent for A and B => C->B repack is
// pure in-lane cvt_pkrtz. Per-step exact pow-2 renorm folded into diag(E).
// amdgpu_waves_per_eu(2): register budget 256/wave so the ~166-reg loop state
// stays in arch VGPRs (default budget 96 caused AGPR bounce moves ~300
// instr/step; occupancy is grid-limited at ~2.75 waves/SIMD either way).

typedef _Float16 h2 __attribute__((ext_vector_type(2)));
typedef _Float16 half8 __attribute__((ext_vector_type(8)));
typedef float f32x4 __attribute__((ext_vector_type(4)));
typedef unsigned u32x2 __attribute__((ext_vector_type(2)));
typedef unsigned u32x4 __attribute__((ext_vector_type(4)));

#define B2U(x) __builtin_bit_cast(unsigned, x)
#define U2H(x) __builtin_bit_cast(h2, x)
#define L2E 1.44269504088896340736f
#define LN2 0.69314718055994530942f
#define EXPE(p) __builtin_amdgcn_exp2f((p) * L2E)
#define SBAR __builtin_amdgcn_sched_barrier(0)

// ---------------- vector-chain machinery (unchanged, verified) ----------------

#define W_ALL(M) M(0) M(1) M(2) M(3) M(4) M(5) M(6) M(7) M(8) M(9) M(10) M(11) \
 M(12) M(13) M(14) M(15) M(16) M(17) M(18) M(19) M(20) M(21) M(22) M(23) M(24) \
 M(25) M(26) M(27) M(28) M(29) M(30) M(31)

#define DECLW(q) unsigned W##q;
#define LOADF(q) W##q = B2U(__builtin_amdgcn_cvt_pkrtz(EXPE(tcol[(2*(q))*66]), EXPE(tcol[(2*(q)+1)*66])));
#define LOADB(q) W##q = B2U(__builtin_amdgcn_cvt_pkrtz(EXPE(trow[2*(q)]), EXPE(trow[2*(q)+1])));
#define PINW(q)  asm volatile("" : "+v"(W##q));

#define RLD(q) int u##q = __builtin_amdgcn_readlane((int)P, 2*(q));
#define RL16A RLD(0) RLD(1) RLD(2) RLD(3) RLD(4) RLD(5) RLD(6) RLD(7) \
              RLD(8) RLD(9) RLD(10) RLD(11) RLD(12) RLD(13) RLD(14) RLD(15)
#define RL16B RLD(16) RLD(17) RLD(18) RLD(19) RLD(20) RLD(21) RLD(22) RLD(23) \
              RLD(24) RLD(25) RLD(26) RLD(27) RLD(28) RLD(29) RLD(30) RLD(31)

#if __has_builtin(__builtin_amdgcn_fdot2)
#define DOTQ(q, acc) acc = __builtin_amdgcn_fdot2(U2H((unsigned)u##q), U2H(W##q), acc, false);
#else
#define DOTQ(q, acc) { h2 _u = U2H((unsigned)u##q), _w = U2H(W##q); \
    acc = fmaf((float)_u[0], (float)_w[0], fmaf((float)_u[1], (float)_w[1], acc)); }
#endif
#define DOT16A \
    DOTQ(0,s0)  DOTQ(1,s1)  DOTQ(2,s2)  DOTQ(3,s3)  DOTQ(4,s0)  DOTQ(5,s1) \
    DOTQ(6,s2)  DOTQ(7,s3)  DOTQ(8,s0)  DOTQ(9,s1)  DOTQ(10,s2) DOTQ(11,s3) \
    DOTQ(12,s0) DOTQ(13,s1) DOTQ(14,s2) DOTQ(15,s3)
#define DOT16B \
    DOTQ(16,s0) DOTQ(17,s1) DOTQ(18,s2) DOTQ(19,s3) DOTQ(20,s0) DOTQ(21,s1) \
    DOTQ(22,s2) DOTQ(23,s3) DOTQ(24,s0) DOTQ(25,s1) DOTQ(26,s2) DOTQ(27,s3) \
    DOTQ(28,s0) DOTQ(29,s1) DOTQ(30,s2) DOTQ(31,s3)

#define ROWF(i) pb[(((i) < 0) ? 0 : (((i) > 1023) ? 1023 : (i))) * 64]

#define DPPSWAP(x) __uint_as_float((unsigned)__builtin_amdgcn_mov_dpp( \
    (int)__float_as_uint(x), 0xB1, 0xF, 0xF, true))

#define STEPX(E) { \
    unsigned abits = (unsigned)__builtin_amdgcn_readfirstlane((int)__float_as_uint(a)); \
    int k = (int)((abits >> 23) & 255u) - 122; \
    K += k; \
    float sc = __uint_as_float((unsigned)(127 - k) << 23); \
    float x = FWD ? a * sc : (a * sc) * (E); \
    float xo = DPPSWAP(x); \
    unsigned P = B2U(__builtin_amdgcn_cvt_pkrtz(x, xo)); \
    float s0 = 0.f, s1 = 0.f, s2 = 0.f, s3 = 0.f; \
    RL16A \
    SBAR; \
    DOT16A \
    RL16B \
    SBAR; \
    DOT16B \
    float s = (s0 + s1) + (s2 + s3); \
    a = FWD ? s * (E) : s; }

template<bool FWD>
__device__ __forceinline__ void chain(const float* __restrict__ pred,
                                      const float* __restrict__ trans,
                                      int b, int lane, int sl, int h,
                                      float* __restrict__ wsV,
                                      int* __restrict__ wsK)
{
    const float* pb   = pred + (size_t)b * 65536 + lane;
    const float* tcol = trans + lane;        // fwd: V[i][lane]
    const float* trow = trans + lane * 66;   // bwd: V[lane][i]
    (void)tcol; (void)trow;

    W_ALL(DECLW)
    if (FWD) { W_ALL(LOADF) } else { W_ALL(LOADB) }
    W_ALL(PINW)

    float a;
    int   K = 0;
    if (FWD) a = __builtin_amdgcn_exp2f((pb[0] + trans[64 * 66 + lane]) * L2E);
    else     a = __builtin_amdgcn_exp2f(trow[65] * L2E);

    const int dir = FWD ? 1 : -1;
    int n = FWD ? h - 1 : sl - h;
    int r = FWD ? 1 : sl - 1;

    float E0 = EXPE(ROWF(r)), E1 = EXPE(ROWF(r + dir)),
          E2 = EXPE(ROWF(r + 2 * dir)), E3 = EXPE(ROWF(r + 3 * dir));
    while (n >= 4) {
        float F0 = ROWF(r + 4 * dir), F1 = ROWF(r + 5 * dir),
              F2 = ROWF(r + 6 * dir), F3 = ROWF(r + 7 * dir);
        STEPX(E0) STEPX(E1) STEPX(E2) STEPX(E3)
        E0 = EXPE(F0); E1 = EXPE(F1); E2 = EXPE(F2); E3 = EXPE(F3);
        r += 4 * dir; n -= 4;
    }
    if (n > 0) { STEPX(E0) --n; }
    if (n > 0) { STEPX(E1) --n; }
    if (n > 0) { STEPX(E2) }

    wsV[b * 64 + lane] = a;
    if (lane == 0) wsK[b] = K;
}

// ---------------- matrix-segment machinery (16x16x32, zero-shuffle repack) ----

#define MF32(a, b, c) __builtin_amdgcn_mfma_f32_16x16x32_f16(a, b, c, 0, 0, 0)

// slot->k bijection within a 32-k slice: e<4 -> 4H+e ; e>=4 -> 16+4H+(e-4)
#define KG(ks, H, e) (32*(ks) + (((e) < 4) ? (4*(H) + (e)) : (16 + 4*(H) + (e) - 4)))

template<int LOGG, int NSLOT>
__device__ __forceinline__ void midseg(const float* __restrict__ pred,
                                       const float* __restrict__ trans,
                                       int b, int lane, int sl, int s,
                                       _Float16* __restrict__ wsM,
                                       int* __restrict__ wsKm)
{
    const int G  = 1 << LOGG;
    const int nm = (sl - G) >> LOGG;
    if (s >= nm) return;
    const int t0 = G * (1 + s);
    const int H  = lane >> 4;       // 0..3
    const int j0 = lane & 15;

    const f32x4 Z4 = {0.f, 0.f, 0.f, 0.f};

    // A-basis: VA[mb][ks] slot e holds exp(trans[KG(ks,H,e)][16mb+j0]).
    half8 VA[4][2];
    #pragma unroll
    for (int mb = 0; mb < 4; ++mb)
        #pragma unroll
        for (int ks = 0; ks < 2; ++ks) {
            const float* tp = trans + 16*mb + j0;
            u32x4 q;
            q.x = B2U(__builtin_amdgcn_cvt_pkrtz(EXPE(tp[KG(ks,H,0)*66]), EXPE(tp[KG(ks,H,1)*66])));
            q.y = B2U(__builtin_amdgcn_cvt_pkrtz(EXPE(tp[KG(ks,H,2)*66]), EXPE(tp[KG(ks,H,3)*66])));
            q.z = B2U(__builtin_amdgcn_cvt_pkrtz(EXPE(tp[KG(ks,H,4)*66]), EXPE(tp[KG(ks,H,5)*66])));
            q.w = B2U(__builtin_amdgcn_cvt_pkrtz(EXPE(tp[KG(ks,H,6)*66]), EXPE(tp[KG(ks,H,7)*66])));
            VA[mb][ks] = __builtin_bit_cast(half8, q);
        }

    // B starts as identity (same slot->k bijection).
    half8 Bf[2][4];   // [ks][nb]
    #pragma unroll
    for (int ks = 0; ks < 2; ++ks)
        #pragma unroll
        for (int nb = 0; nb < 4; ++nb) {
            half8 bb;
            #pragma unroll
            for (int e = 0; e < 8; ++e)
                bb[e] = (KG(ks, H, e) == 16*nb + j0) ? (_Float16)1.f
                                                     : (_Float16)0.f;
            Bf[ks][nb] = bb;
        }

    const float* pp = pred + (size_t)b * 65536 + j0;
    float eA0 = EXPE(pp[(size_t)t0*64]),      eA1 = EXPE(pp[(size_t)t0*64+16]),
          eA2 = EXPE(pp[(size_t)t0*64+32]),   eA3 = EXPE(pp[(size_t)t0*64+48]);
    float eB0 = EXPE(pp[(size_t)(t0+1)*64]),    eB1 = EXPE(pp[(size_t)(t0+1)*64+16]),
          eB2 = EXPE(pp[(size_t)(t0+1)*64+32]), eB3 = EXPE(pp[(size_t)(t0+1)*64+48]);

    f32x4 C[4][4];
    #pragma unroll
    for (int mb = 0; mb < 4; ++mb)
        #pragma unroll
        for (int nb = 0; nb < 4; ++nb)
            C[mb][nb] = Z4;

    int   K   = 0;
    float scf = 1.0f;

    for (int i = 0; i < G; ++i) {
        int tn = t0 + i + 2; if (tn > 1023) tn = 1023;
        float g0 = pp[(size_t)tn*64],    g1 = pp[(size_t)tn*64+16],
              g2 = pp[(size_t)tn*64+32], g3 = pp[(size_t)tn*64+48];

        if (i > 0) {
            // renorm ref: 16 rows {0-3,16-19,32-35,48-51} of col 0 at lane 0
            float sr = ((C[0][0][0]+C[0][0][1])+(C[0][0][2]+C[0][0][3]))
                     + ((C[1][0][0]+C[1][0][1])+(C[1][0][2]+C[1][0][3]))
                     + ((C[2][0][0]+C[2][0][1])+(C[2][0][2]+C[2][0][3]))
                     + ((C[3][0][0]+C[3][0][1])+(C[3][0][2]+C[3][0][3]));
            unsigned cb = (unsigned)__builtin_amdgcn_readfirstlane((int)__float_as_uint(sr));
            int kk = (int)((cb >> 23) & 255u) - 129;   // ilogb(sr) - 2
            K += kk;
            scf = __uint_as_float((unsigned)(127 - kk) << 23);
            // C -> B: pure in-lane cvt. Bf(ks,nb) = concat(C[2ks][nb], C[2ks+1][nb])
            #pragma unroll
            for (int ks = 0; ks < 2; ++ks)
                #pragma unroll
                for (int nb = 0; nb < 4; ++nb) {
                    u32x4 q;
                    q.x = B2U(__builtin_amdgcn_cvt_pkrtz(C[2*ks][nb][0],   C[2*ks][nb][1]));
                    q.y = B2U(__builtin_amdgcn_cvt_pkrtz(C[2*ks][nb][2],   C[2*ks][nb][3]));
                    q.z = B2U(__builtin_amdgcn_cvt_pkrtz(C[2*ks+1][nb][0], C[2*ks+1][nb][1]));
                    q.w = B2U(__builtin_amdgcn_cvt_pkrtz(C[2*ks+1][nb][2], C[2*ks+1][nb][3]));
                    Bf[ks][nb] = __builtin_bit_cast(half8, q);
                }
        }

        // E row-scale, one cvt per row-block + splat
        unsigned p0 = B2U(__builtin_amdgcn_cvt_pkrtz(eA0*scf, eA0*scf));
        unsigned p1 = B2U(__builtin_amdgcn_cvt_pkrtz(eA1*scf, eA1*scf));
        unsigned p2 = B2U(__builtin_amdgcn_cvt_pkrtz(eA2*scf, eA2*scf));
        unsigned p3 = B2U(__builtin_amdgcn_cvt_pkrtz(eA3*scf, eA3*scf));
        half8 E0 = __builtin_bit_cast(half8, (u32x4){p0,p0,p0,p0});
        half8 E1 = __builtin_bit_cast(half8, (u32x4){p1,p1,p1,p1});
        half8 E2 = __builtin_bit_cast(half8, (u32x4){p2,p2,p2,p2});
        half8 E3 = __builtin_bit_cast(half8, (u32x4){p3,p3,p3,p3});

        // C rebuilt in place (Bf already captured old C)
        {
            half8 A0 = VA[0][0]*E0, A1 = VA[0][1]*E0;
            #pragma unroll
            for (int nb = 0; nb < 4; ++nb) {
                f32x4 t = MF32(A0, Bf[0][nb], Z4);
                C[0][nb] = MF32(A1, Bf[1][nb], t);
            }
        }
        {
            half8 A0 = VA[1][0]*E1, A1 = VA[1][1]*E1;
            #pragma unroll
            for (int nb = 0; nb < 4; ++nb) {
                f32x4 t = MF32(A0, Bf[0][nb], Z4);
                C[1][nb] = MF32(A1, Bf[1][nb], t);
            }
        }
        {
            half8 A0 = VA[2][0]*E2, A1 = VA[2][1]*E2;
            #pragma unroll
            for (int nb = 0; nb < 4; ++nb) {
                f32x4 t = MF32(A0, Bf[0][nb], Z4);
                C[2][nb] = MF32(A1, Bf[1][nb], t);
            }
        }
        {
            half8 A0 = VA[3][0]*E3, A1 = VA[3][1]*E3;
            #pragma unroll
            for (int nb = 0; nb < 4; ++nb) {
                f32x4 t = MF32(A0, Bf[0][nb], Z4);
                C[3][nb] = MF32(A1, Bf[1][nb], t);
            }
        }

        eA0 = eB0; eA1 = eB1; eA2 = eB2; eA3 = eB3;
        eB0 = EXPE(g0); eB1 = EXPE(g1); eB2 = EXPE(g2); eB3 = EXPE(g3);
    }

    // store M_s row-major f16 [64][64]
    _Float16* wm = wsM + ((size_t)b * NSLOT + s) * 4096;
    #pragma unroll
    for (int mb = 0; mb < 4; ++mb)
        #pragma unroll
        for (int nb = 0; nb < 4; ++nb)
            #pragma unroll
            for (int r = 0; r < 4; ++r)
                wm[(16*mb + 4*H + r) * 64 + 16*nb + j0] = (_Float16)C[mb][nb][r];
    if (lane == 0) wsKm[b * NSLOT + s] = K;
}

// ---------------- kernels ----------------

template<int LOGG, int NSLOT>
__global__ __launch_bounds__(64) __attribute__((amdgpu_waves_per_eu(2)))
void chain_kernel(const float* __restrict__ pred,
                  const float* __restrict__ trans,
                  const int*   __restrict__ ref,
                  const int*   __restrict__ seqlen,
                  float* __restrict__ wsA, float* __restrict__ wsB,
                  int* __restrict__ wsKf, int* __restrict__ wsKb,
                  _Float16* __restrict__ wsM, int* __restrict__ wsKm,
                  float* __restrict__ out)
{
    const int role = blockIdx.x >> 8;
    const int b    = blockIdx.x & 255;
    const int lane = threadIdx.x;
    const int sl   = seqlen[b];
    const int G    = 1 << LOGG;

    if (role == 0) {
        chain<true>(pred, trans, b, lane, sl, G, wsA, wsKf);
    } else if (role == 1) {
        const int nm = (sl - G) >> LOGG;
        chain<false>(pred, trans, b, lane, sl, G * (1 + nm), wsB, wsKb);
    } else if (role == 2) {
        // gold-path score
        const int*   rb = ref  + b * 1024;
        const float* pg = pred + (size_t)b * 65536;
        float acc = 0.f;
        for (int t = lane; t <= sl; t += 64) {
            int from = (t == 0) ? 64 : rb[t - 1];
            int cur  = (t < sl) ? rb[t] : 65;
            acc += trans[from * 66 + cur];
            if (t < sl) acc += pg[t * 64 + cur];
        }
        #pragma unroll
        for (int off = 32; off; off >>= 1) acc += __shfl_xor(acc, off, 64);
        if (lane == 0) atomicAdd(out, -acc);
    } else {
        midseg<LOGG, NSLOT>(pred, trans, b, lane, sl, role - 3, wsM, wsKm);
    }
}

template<int LOGG, int NSLOT>
__global__ __launch_bounds__(64) void combine_kernel(
    const float* __restrict__ wsA, const float* __restrict__ wsB,
    const _Float16* __restrict__ wsM,
    const int* __restrict__ wsKf, const int* __restrict__ wsKb,
    const int* __restrict__ wsKm, const int* __restrict__ seqlen,
    float* __restrict__ out)
{
    const int b = blockIdx.x, j = threadIdx.x;
    const int sl = seqlen[b];
    const int nm = (sl - (1 << LOGG)) >> LOGG;

    float v = wsA[b * 64 + j];
    int   K = wsKf[b] + wsKb[b];
    const _Float16* mrow = wsM + (size_t)b * NSLOT * 4096 + j * 64;  // row j

    for (int s = 0; s < nm; ++s) {
        K += wsKm[b * NSLOT + s];
        const u32x4* mp = (const u32x4*)(mrow + (size_t)s * 4096);
        u32x4 L0 = mp[0], L1 = mp[1], L2 = mp[2], L3 = mp[3],
              L4 = mp[4], L5 = mp[5], L6 = mp[6], L7 = mp[7];
        unsigned mw[32] = {L0.x,L0.y,L0.z,L0.w, L1.x,L1.y,L1.z,L1.w,
                           L2.x,L2.y,L2.z,L2.w, L3.x,L3.y,L3.z,L3.w,
                           L4.x,L4.y,L4.z,L4.w, L5.x,L5.y,L5.z,L5.w,
                           L6.x,L6.y,L6.z,L6.w, L7.x,L7.y,L7.z,L7.w};
        float av[4] = {0.f, 0.f, 0.f, 0.f};
        #pragma unroll
        for (int q = 0; q < 32; ++q) {
            h2 p = U2H(mw[q]);
            float v0 = __uint_as_float((unsigned)
                __builtin_amdgcn_readlane((int)__float_as_uint(v), 2*q));
            float v1 = __uint_as_float((unsigned)
                __builtin_amdgcn_readlane((int)__float_as_uint(v), 2*q + 1));
            av[q & 3] = fmaf((float)p[0], v0, fmaf((float)p[1], v1, av[q & 3]));
        }
        float acc = (av[0] + av[1]) + (av[2] + av[3]);
        unsigned ab = (unsigned)__builtin_amdgcn_readfirstlane((int)__float_as_uint(acc));
        int k2 = (int)((ab >> 23) & 255u) - 127;
        K += k2;
        v = acc * __uint_as_float((unsigned)(127 - k2) << 23);
    }

    float z = v * wsB[b * 64 + j];
    #pragma unroll
    for (int off = 32; off; off >>= 1) z += __shfl_xor(z, off, 64);
    if (j == 0) {
        float res = LN2 * (__builtin_amdgcn_logf(z) + (float)K);
        atomicAdd(out, res);
    }
}

// ---------------- launch ----------------

template<int LOGG, int NSLOT>
static void launch_all(const float* pred, const float* trans, const int* ref,
                       const int* seqlen, float* out, void* d_ws,
                       hipStream_t stream)
{
    float* wsA  = (float*)d_ws;            // 256*64 f32
    float* wsB  = wsA + 256 * 64;          // 256*64 f32
    int*   wsKf = (int*)(wsB + 256 * 64);  // 256 i32
    int*   wsKb = wsKf + 256;              // 256 i32
    int*   wsKm = wsKb + 256;              // 256*NSLOT i32
    _Float16* wsM = (_Float16*)(wsKm + 256 * NSLOT);  // 256*NSLOT*4096 f16

    hipMemsetAsync(out, 0, sizeof(float), stream);
    chain_kernel<LOGG, NSLOT><<<256 * (3 + NSLOT), 64, 0, stream>>>(
        pred, trans, ref, seqlen, wsA, wsB, wsKf, wsKb, wsM, wsKm, out);
    combine_kernel<LOGG, NSLOT><<<256, 64, 0, stream>>>(
        wsA, wsB, wsM, wsKf, wsKb, wsKm, seqlen, out);
}

extern "C" void kernel_launch(void* const* d_in, const int* in_sizes, int n_in,
                              void* d_out, int out_size, void* d_ws, size_t ws_size,
                              hipStream_t stream) {
    const float* pred   = (const float*)d_in[0];
    const float* trans  = (const float*)d_in[1];
    const int*   ref    = (const int*)d_in[2];
    const int*   seqlen = (const int*)d_in[3];
    float* out = (float*)d_out;

    // G=64 needs 2*64KB + 2*1KB + 15KB + 30MB ≈ 31.6 MB; fall back to the
    // G=128 geometry (14.8 MB) if the workspace is smaller.
    const size_t need64 = 2*65536 + 2*1024 + (size_t)256*15*4
                        + (size_t)256*15*4096*2;
    if (ws_size >= need64)
        launch_all<6, 15>(pred, trans, ref, seqlen, out, d_ws, stream);
    else
        launch_all<7, 7>(pred, trans, ref, seqlen, out, d_ws, stream);
}